// Round 1
// baseline (625.853 us; speedup 1.0000x reference)
//
#include <hip/hip_runtime.h>

#define N_NODES 100000
#define N_EDGES 1600000
#define DIM 64
#define BN_EPS 1e-5f

// ---------------- degree: one thread per edge, int atomics ----------------
__global__ void deg_kernel(const int* __restrict__ dst, int* __restrict__ deg, int E) {
    int e = blockIdx.x * blockDim.x + threadIdx.x;
    if (e < E) atomicAdd(&deg[dst[e]], 1);
}

// ---------------- dinv = rsqrt(deg + 1)  (self-loop included) -------------
__global__ void dinv_kernel(const int* __restrict__ deg, float* __restrict__ dinv, int N) {
    int i = blockIdx.x * blockDim.x + threadIdx.x;
    if (i < N) dinv[i] = rsqrtf((float)(deg[i] + 1));
}

// ---------------- h = x @ W : one wave per row ----------------------------
// lane j computes h[row][j]; x-row broadcast via shuffle; W column reads
// coalesced across lanes and L1-resident (16 KB total).
__global__ void gemm_kernel(const float* __restrict__ x, const float* __restrict__ W,
                            float* __restrict__ h, int N) {
    int gid  = blockIdx.x * blockDim.x + threadIdx.x;
    int row  = gid >> 6;
    int lane = gid & 63;
    if (row >= N) return;  // uniform per wave
    float xv  = x[row * DIM + lane];
    float acc = 0.f;
#pragma unroll
    for (int k = 0; k < DIM; ++k) {
        acc = fmaf(__shfl(xv, k, 64), W[k * DIM + lane], acc);
    }
    h[row * DIM + lane] = acc;
}

// ---------------- edge scatter: wave per edge, lane per feature -----------
__global__ void scatter_kernel(const int* __restrict__ src, const int* __restrict__ dst,
                               const float* __restrict__ h, const float* __restrict__ dinv,
                               float* __restrict__ out, int E) {
    int gid  = blockIdx.x * blockDim.x + threadIdx.x;
    int e    = gid >> 6;
    int lane = gid & 63;
    if (e >= E) return;  // uniform per wave
    int s = src[e];
    int d = dst[e];
    float w = dinv[s] * dinv[d];
    atomicAdd(&out[d * DIM + lane], h[s * DIM + lane] * w);
}

// ---------------- self-loop: exclusive per element, no atomics ------------
__global__ void selfloop_kernel(const float* __restrict__ h, const float* __restrict__ dinv,
                                float* __restrict__ out, int total) {
    int i = blockIdx.x * blockDim.x + threadIdx.x;
    if (i >= total) return;
    int node = i >> 6;
    float w = dinv[node];
    out[i] += h[i] * (w * w);
}

// ---------------- BN reduce: per-column sum / sumsq -----------------------
// bias b cancels in BN (uniform per-column shift), so it's omitted entirely.
__global__ void bn_reduce_kernel(const float* __restrict__ out,
                                 float* __restrict__ gsum, float* __restrict__ gsumsq, int N) {
    __shared__ float ssum[256];
    __shared__ float ssq[256];
    int col = threadIdx.x & 63;
    int sub = threadIdx.x >> 6;  // 0..3
    float s = 0.f, q = 0.f;
    for (int row = blockIdx.x * 4 + sub; row < N; row += gridDim.x * 4) {
        float v = out[row * DIM + col];
        s += v;
        q += v * v;
    }
    ssum[threadIdx.x] = s;
    ssq[threadIdx.x]  = q;
    __syncthreads();
    if (threadIdx.x < 128) {
        ssum[threadIdx.x] += ssum[threadIdx.x + 128];
        ssq[threadIdx.x]  += ssq[threadIdx.x + 128];
    }
    __syncthreads();
    if (threadIdx.x < 64) {
        atomicAdd(&gsum[col],   ssum[threadIdx.x] + ssum[threadIdx.x + 64]);
        atomicAdd(&gsumsq[col], ssq[threadIdx.x]  + ssq[threadIdx.x + 64]);
    }
}

// ---------------- BN finalize: scale/shift per column ---------------------
__global__ void bn_finalize_kernel(const float* __restrict__ gsum, const float* __restrict__ gsumsq,
                                   const float* __restrict__ gamma, const float* __restrict__ beta,
                                   float* __restrict__ scale, float* __restrict__ shift, int N) {
    int c = threadIdx.x;  // 64 threads
    float invN = 1.0f / (float)N;
    float mean = gsum[c] * invN;
    float var  = gsumsq[c] * invN - mean * mean;
    float sc   = gamma[c] * rsqrtf(var + BN_EPS);
    scale[c] = sc;
    shift[c] = beta[c] - mean * sc;
}

// ---------------- BN apply + ReLU, in place -------------------------------
__global__ void bn_apply_kernel(float* __restrict__ out, const float* __restrict__ scale,
                                const float* __restrict__ shift, int total) {
    int i = blockIdx.x * blockDim.x + threadIdx.x;
    if (i >= total) return;
    int c = i & 63;
    float v = fmaf(out[i], scale[c], shift[c]);
    out[i] = v > 0.f ? v : 0.f;
}

extern "C" void kernel_launch(void* const* d_in, const int* in_sizes, int n_in,
                              void* d_out, int out_size, void* d_ws, size_t ws_size,
                              hipStream_t stream) {
    const float* x     = (const float*)d_in[0];          // [N, 64]
    const int*   eidx  = (const int*)d_in[1];            // [2, E]
    const float* W     = (const float*)d_in[2];          // [64, 64]
    // d_in[3] = b : provably cancels in BatchNorm (uniform per-column shift)
    const float* gamma = (const float*)d_in[4];          // [64]
    const float* beta  = (const float*)d_in[5];          // [64]
    float* out = (float*)d_out;                          // [N, 64]

    const int N = N_NODES;
    const int E = N_EDGES;
    const int total = N * DIM;

    const int* src = eidx;
    const int* dst = eidx + E;

    // workspace layout
    float* h      = (float*)d_ws;          // N*DIM
    float* dinv   = h + (size_t)N * DIM;   // N
    int*   deg    = (int*)(dinv + N);      // N
    float* gsum   = (float*)(deg + N);     // 64
    float* gsumsq = gsum + 64;             // 64
    float* scale  = gsumsq + 64;           // 64
    float* shift  = scale + 64;            // 64

    // zero-init accumulators (graph-capture safe)
    hipMemsetAsync(deg, 0, (size_t)N * sizeof(int), stream);
    hipMemsetAsync(gsum, 0, 128 * sizeof(float), stream);
    hipMemsetAsync(out, 0, (size_t)total * sizeof(float), stream);

    deg_kernel<<<(E + 255) / 256, 256, 0, stream>>>(dst, deg, E);
    dinv_kernel<<<(N + 255) / 256, 256, 0, stream>>>(deg, dinv, N);
    gemm_kernel<<<(total + 255) / 256, 256, 0, stream>>>(x, W, h, N);
    {
        long long threads = (long long)E * 64;
        int blocks = (int)((threads + 255) / 256);
        scatter_kernel<<<blocks, 256, 0, stream>>>(src, dst, h, dinv, out, E);
    }
    selfloop_kernel<<<(total + 255) / 256, 256, 0, stream>>>(h, dinv, out, total);
    bn_reduce_kernel<<<512, 256, 0, stream>>>(out, gsum, gsumsq, N);
    bn_finalize_kernel<<<1, 64, 0, stream>>>(gsum, gsumsq, gamma, beta, scale, shift, N);
    bn_apply_kernel<<<(total + 255) / 256, 256, 0, stream>>>(out, scale, shift, total);
}

// Round 2
// 536.588 us; speedup vs baseline: 1.1664x; 1.1664x over previous
//
#include <hip/hip_runtime.h>

#define N_NODES 100000
#define N_EDGES 1600000
#define DIM 64
#define BN_EPS 1e-5f

// ---------------- degree: one thread per edge, int atomics ----------------
__global__ void deg_kernel(const int* __restrict__ dst, int* __restrict__ deg, int E) {
    int e = blockIdx.x * blockDim.x + threadIdx.x;
    if (e < E) atomicAdd(&deg[dst[e]], 1);
}

// ---------------- dinv = rsqrt(deg + 1)  (self-loop included) -------------
__global__ void dinv_kernel(const int* __restrict__ deg, float* __restrict__ dinv, int N) {
    int i = blockIdx.x * blockDim.x + threadIdx.x;
    if (i < N) dinv[i] = rsqrtf((float)(deg[i] + 1));
}

// ---------------- exclusive scan of deg -> rowptr (3-kernel classic) ------
__global__ void scan1_kernel(const int* __restrict__ deg, int* __restrict__ rowptr,
                             int* __restrict__ blocksums, int N) {
    __shared__ int buf[256];
    int t = threadIdx.x;
    int i = blockIdx.x * 256 + t;
    int v = (i < N) ? deg[i] : 0;
    buf[t] = v;
    __syncthreads();
#pragma unroll
    for (int off = 1; off < 256; off <<= 1) {
        int add = (t >= off) ? buf[t - off] : 0;
        __syncthreads();
        buf[t] += add;
        __syncthreads();
    }
    if (i < N) rowptr[i] = buf[t] - v;  // exclusive within block
    if (t == 255) blocksums[blockIdx.x] = buf[255];
}

__global__ void scan2_kernel(int* __restrict__ blocksums, int nb) {
    __shared__ int buf[512];
    int t = threadIdx.x;
    int v = (t < nb) ? blocksums[t] : 0;
    buf[t] = v;
    __syncthreads();
#pragma unroll
    for (int off = 1; off < 512; off <<= 1) {
        int add = (t >= off) ? buf[t - off] : 0;
        __syncthreads();
        buf[t] += add;
        __syncthreads();
    }
    if (t < nb) blocksums[t] = buf[t] - v;  // exclusive
}

__global__ void scan3_kernel(int* __restrict__ rowptr, int* __restrict__ cursor,
                             const int* __restrict__ blocksums, int N, int E) {
    int i = blockIdx.x * blockDim.x + threadIdx.x;
    if (i < N) {
        int v = rowptr[i] + blocksums[i >> 8];
        rowptr[i] = v;
        cursor[i] = v;
    }
    if (i == N) rowptr[N] = E;
}

// ---------------- h = x @ W : one wave per row ----------------------------
__global__ void gemm_kernel(const float* __restrict__ x, const float* __restrict__ W,
                            float* __restrict__ h, int N) {
    int gid  = blockIdx.x * blockDim.x + threadIdx.x;
    int row  = gid >> 6;
    int lane = gid & 63;
    if (row >= N) return;  // uniform per wave
    float xv  = x[row * DIM + lane];
    float acc = 0.f;
#pragma unroll
    for (int k = 0; k < DIM; ++k) {
        acc = fmaf(__shfl(xv, k, 64), W[k * DIM + lane], acc);
    }
    h[row * DIM + lane] = acc;
}

// ---------------- bucket edges into CSR (counting sort by dst) ------------
__global__ void bucket_kernel(const int* __restrict__ src, const int* __restrict__ dst,
                              const float* __restrict__ dinv, int* __restrict__ cursor,
                              int* __restrict__ csr_src, float* __restrict__ csr_w, int E) {
    int e = blockIdx.x * blockDim.x + threadIdx.x;
    if (e >= E) return;
    int s = src[e];
    int d = dst[e];
    int pos = atomicAdd(&cursor[d], 1);
    csr_src[pos] = s;
    csr_w[pos]   = dinv[s] * dinv[d];
}

// ---------------- gather: wave per node, lane per feature, atomic-free ----
__global__ void gather_kernel(const int* __restrict__ rowptr, const int* __restrict__ csr_src,
                              const float* __restrict__ csr_w, const float* __restrict__ h,
                              const float* __restrict__ dinv, float* __restrict__ out, int N) {
    int gid  = blockIdx.x * blockDim.x + threadIdx.x;
    int node = gid >> 6;
    int lane = gid & 63;
    if (node >= N) return;  // uniform per wave
    float di  = dinv[node];
    float acc = h[node * DIM + lane] * (di * di);  // self loop
    int beg = rowptr[node];
    int end = rowptr[node + 1];
    for (int i = beg; i < end; ++i) {
        int s   = csr_src[i];
        float w = csr_w[i];
        acc = fmaf(h[s * DIM + lane], w, acc);
    }
    out[node * DIM + lane] = acc;
}

// ---------------- BN reduce: per-column sum / sumsq -----------------------
// bias b cancels in BN (uniform per-column shift), so it's omitted entirely.
__global__ void bn_reduce_kernel(const float* __restrict__ out,
                                 float* __restrict__ gsum, float* __restrict__ gsumsq, int N) {
    __shared__ float ssum[256];
    __shared__ float ssq[256];
    int col = threadIdx.x & 63;
    int sub = threadIdx.x >> 6;  // 0..3
    float s = 0.f, q = 0.f;
    for (int row = blockIdx.x * 4 + sub; row < N; row += gridDim.x * 4) {
        float v = out[row * DIM + col];
        s += v;
        q += v * v;
    }
    ssum[threadIdx.x] = s;
    ssq[threadIdx.x]  = q;
    __syncthreads();
    if (threadIdx.x < 128) {
        ssum[threadIdx.x] += ssum[threadIdx.x + 128];
        ssq[threadIdx.x]  += ssq[threadIdx.x + 128];
    }
    __syncthreads();
    if (threadIdx.x < 64) {
        atomicAdd(&gsum[col],   ssum[threadIdx.x] + ssum[threadIdx.x + 64]);
        atomicAdd(&gsumsq[col], ssq[threadIdx.x]  + ssq[threadIdx.x + 64]);
    }
}

// ---------------- BN finalize: scale/shift per column ---------------------
__global__ void bn_finalize_kernel(const float* __restrict__ gsum, const float* __restrict__ gsumsq,
                                   const float* __restrict__ gamma, const float* __restrict__ beta,
                                   float* __restrict__ scale, float* __restrict__ shift, int N) {
    int c = threadIdx.x;  // 64 threads
    float invN = 1.0f / (float)N;
    float mean = gsum[c] * invN;
    float var  = gsumsq[c] * invN - mean * mean;
    float sc   = gamma[c] * rsqrtf(var + BN_EPS);
    scale[c] = sc;
    shift[c] = beta[c] - mean * sc;
}

// ---------------- BN apply + ReLU, in place -------------------------------
__global__ void bn_apply_kernel(float* __restrict__ out, const float* __restrict__ scale,
                                const float* __restrict__ shift, int total) {
    int i = blockIdx.x * blockDim.x + threadIdx.x;
    if (i >= total) return;
    int c = i & 63;
    float v = fmaf(out[i], scale[c], shift[c]);
    out[i] = v > 0.f ? v : 0.f;
}

extern "C" void kernel_launch(void* const* d_in, const int* in_sizes, int n_in,
                              void* d_out, int out_size, void* d_ws, size_t ws_size,
                              hipStream_t stream) {
    const float* x     = (const float*)d_in[0];          // [N, 64]
    const int*   eidx  = (const int*)d_in[1];            // [2, E]
    const float* W     = (const float*)d_in[2];          // [64, 64]
    // d_in[3] = b : cancels in BatchNorm (uniform per-column shift)
    const float* gamma = (const float*)d_in[4];          // [64]
    const float* beta  = (const float*)d_in[5];          // [64]
    float* out = (float*)d_out;                          // [N, 64]

    const int N = N_NODES;
    const int E = N_EDGES;
    const int total = N * DIM;

    const int* src = eidx;
    const int* dst = eidx + E;

    // workspace layout (~40 MB)
    float* h        = (float*)d_ws;              // N*DIM
    float* dinv     = h + (size_t)N * DIM;       // N
    int*   deg      = (int*)(dinv + N);          // N
    int*   rowptr   = deg + N;                   // N+1
    int*   cursor   = rowptr + N + 1;            // N
    int*   blocksums= cursor + N;                // 512
    int*   csr_src  = blocksums + 512;           // E
    float* csr_w    = (float*)(csr_src + E);     // E
    float* gsum     = csr_w + E;                 // 64
    float* gsumsq   = gsum + 64;                 // 64
    float* scale    = gsumsq + 64;               // 64
    float* shift    = scale + 64;                // 64

    hipMemsetAsync(deg, 0, (size_t)N * sizeof(int), stream);
    hipMemsetAsync(gsum, 0, 128 * sizeof(float), stream);

    deg_kernel<<<(E + 255) / 256, 256, 0, stream>>>(dst, deg, E);
    dinv_kernel<<<(N + 255) / 256, 256, 0, stream>>>(deg, dinv, N);

    int nb = (N + 255) / 256;  // 391
    scan1_kernel<<<nb, 256, 0, stream>>>(deg, rowptr, blocksums, N);
    scan2_kernel<<<1, 512, 0, stream>>>(blocksums, nb);
    scan3_kernel<<<(N + 256) / 256, 256, 0, stream>>>(rowptr, cursor, blocksums, N, E);

    gemm_kernel<<<(total + 255) / 256, 256, 0, stream>>>(x, W, h, N);

    bucket_kernel<<<(E + 255) / 256, 256, 0, stream>>>(src, dst, dinv, cursor, csr_src, csr_w, E);

    gather_kernel<<<(total + 255) / 256, 256, 0, stream>>>(rowptr, csr_src, csr_w, h, dinv, out, N);

    bn_reduce_kernel<<<512, 256, 0, stream>>>(out, gsum, gsumsq, N);
    bn_finalize_kernel<<<1, 64, 0, stream>>>(gsum, gsumsq, gamma, beta, scale, shift, N);
    bn_apply_kernel<<<(total + 255) / 256, 256, 0, stream>>>(out, scale, shift, total);
}

// Round 3
// 447.133 us; speedup vs baseline: 1.3997x; 1.2001x over previous
//
#include <hip/hip_runtime.h>

#define N_NODES 100000
#define N_EDGES 1600000
#define DIM 64
#define BN_EPS 1e-5f

// ---- bf16 helpers (manual RNE, no NaN concerns here) ---------------------
static __device__ __forceinline__ unsigned short f2bf(float f) {
    unsigned u = __float_as_uint(f);
    u = (u + 0x7FFFu + ((u >> 16) & 1u)) >> 16;
    return (unsigned short)u;
}
static __device__ __forceinline__ float bf2f(unsigned short h) {
    return __uint_as_float(((unsigned)h) << 16);
}

// ---------------- degree: one thread per edge, int atomics ----------------
__global__ void deg_kernel(const int* __restrict__ dst, int* __restrict__ deg, int E) {
    int e = blockIdx.x * blockDim.x + threadIdx.x;
    if (e < E) atomicAdd(&deg[dst[e]], 1);
}

// ---------------- scan1 + fused dinv --------------------------------------
__global__ void scan1_kernel(const int* __restrict__ deg, int* __restrict__ rowptr,
                             int* __restrict__ blocksums, float* __restrict__ dinv, int N) {
    __shared__ int buf[256];
    int t = threadIdx.x;
    int i = blockIdx.x * 256 + t;
    int v = (i < N) ? deg[i] : 0;
    if (i < N) dinv[i] = rsqrtf((float)(v + 1));  // self-loop included
    buf[t] = v;
    __syncthreads();
#pragma unroll
    for (int off = 1; off < 256; off <<= 1) {
        int add = (t >= off) ? buf[t - off] : 0;
        __syncthreads();
        buf[t] += add;
        __syncthreads();
    }
    if (i < N) rowptr[i] = buf[t] - v;  // exclusive within block
    if (t == 255) blocksums[blockIdx.x] = buf[255];
}

__global__ void scan2_kernel(int* __restrict__ blocksums, int nb) {
    __shared__ int buf[512];
    int t = threadIdx.x;
    int v = (t < nb) ? blocksums[t] : 0;
    buf[t] = v;
    __syncthreads();
#pragma unroll
    for (int off = 1; off < 512; off <<= 1) {
        int add = (t >= off) ? buf[t - off] : 0;
        __syncthreads();
        buf[t] += add;
        __syncthreads();
    }
    if (t < nb) blocksums[t] = buf[t] - v;  // exclusive
}

__global__ void scan3_kernel(int* __restrict__ rowptr, int* __restrict__ cursor,
                             const int* __restrict__ blocksums, int N, int E) {
    int i = blockIdx.x * blockDim.x + threadIdx.x;
    if (i < N) {
        int v = rowptr[i] + blocksums[i >> 8];
        rowptr[i] = v;
        cursor[i] = v;
    }
    if (i == N) rowptr[N] = E;
}

// ---------------- h' = (x @ W) * dinv[row], stored bf16 -------------------
__global__ void gemm_kernel(const float* __restrict__ x, const float* __restrict__ W,
                            const float* __restrict__ dinv, unsigned short* __restrict__ hb,
                            int N) {
    int gid  = blockIdx.x * blockDim.x + threadIdx.x;
    int row  = gid >> 6;
    int lane = gid & 63;
    if (row >= N) return;  // uniform per wave
    float xv  = x[row * DIM + lane];
    float acc = 0.f;
#pragma unroll
    for (int k = 0; k < DIM; ++k) {
        acc = fmaf(__shfl(xv, k, 64), W[k * DIM + lane], acc);
    }
    hb[row * DIM + lane] = f2bf(acc * dinv[row]);
}

// ---------------- bucket edges into CSR (counting sort by dst) ------------
__global__ void bucket_kernel(const int* __restrict__ src, const int* __restrict__ dst,
                              int* __restrict__ cursor, int* __restrict__ csr_src, int E) {
    int e = blockIdx.x * blockDim.x + threadIdx.x;
    if (e >= E) return;
    int d = dst[e];
    int pos = atomicAdd(&cursor[d], 1);
    csr_src[pos] = src[e];
}

// ---------------- gather: wave/node, lane/feature, batched indices --------
__global__ void gather_kernel(const int* __restrict__ rowptr, const int* __restrict__ csr_src,
                              const unsigned short* __restrict__ hb,
                              const float* __restrict__ dinv, float* __restrict__ out, int N) {
    int gid  = blockIdx.x * blockDim.x + threadIdx.x;
    int node = gid >> 6;
    int lane = gid & 63;
    if (node >= N) return;  // uniform per wave
    float acc = bf2f(hb[node * DIM + lane]);  // self loop (h' already has dinv[node])
    int beg = rowptr[node];
    int end = rowptr[node + 1];
    for (int base = beg; base < end; base += 64) {
        int idx = base + lane;
        int sv  = (idx < end) ? csr_src[idx] : 0;  // coalesced batch of indices
        int cnt = min(64, end - base);
        int j = 0;
        for (; j + 4 <= cnt; j += 4) {
            int s0 = __shfl(sv, j,     64);
            int s1 = __shfl(sv, j + 1, 64);
            int s2 = __shfl(sv, j + 2, 64);
            int s3 = __shfl(sv, j + 3, 64);
            float v0 = bf2f(hb[s0 * DIM + lane]);
            float v1 = bf2f(hb[s1 * DIM + lane]);
            float v2 = bf2f(hb[s2 * DIM + lane]);
            float v3 = bf2f(hb[s3 * DIM + lane]);
            acc += (v0 + v1) + (v2 + v3);
        }
        for (; j < cnt; ++j) {
            int s = __shfl(sv, j, 64);
            acc += bf2f(hb[s * DIM + lane]);
        }
    }
    out[node * DIM + lane] = acc * dinv[node];
}

// ---------------- BN reduce: per-column sum / sumsq -----------------------
// bias b cancels in BN (uniform per-column shift), so it's omitted entirely.
__global__ void bn_reduce_kernel(const float* __restrict__ out,
                                 float* __restrict__ gsum, float* __restrict__ gsumsq, int N) {
    __shared__ float ssum[256];
    __shared__ float ssq[256];
    int col = threadIdx.x & 63;
    int sub = threadIdx.x >> 6;  // 0..3
    float s = 0.f, q = 0.f;
    for (int row = blockIdx.x * 4 + sub; row < N; row += gridDim.x * 4) {
        float v = out[row * DIM + col];
        s += v;
        q += v * v;
    }
    ssum[threadIdx.x] = s;
    ssq[threadIdx.x]  = q;
    __syncthreads();
    if (threadIdx.x < 128) {
        ssum[threadIdx.x] += ssum[threadIdx.x + 128];
        ssq[threadIdx.x]  += ssq[threadIdx.x + 128];
    }
    __syncthreads();
    if (threadIdx.x < 64) {
        atomicAdd(&gsum[col],   ssum[threadIdx.x] + ssum[threadIdx.x + 64]);
        atomicAdd(&gsumsq[col], ssq[threadIdx.x]  + ssq[threadIdx.x + 64]);
    }
}

// ---------------- BN finalize: scale/shift per column ---------------------
__global__ void bn_finalize_kernel(const float* __restrict__ gsum, const float* __restrict__ gsumsq,
                                   const float* __restrict__ gamma, const float* __restrict__ beta,
                                   float* __restrict__ scale, float* __restrict__ shift, int N) {
    int c = threadIdx.x;  // 64 threads
    float invN = 1.0f / (float)N;
    float mean = gsum[c] * invN;
    float var  = gsumsq[c] * invN - mean * mean;
    float sc   = gamma[c] * rsqrtf(var + BN_EPS);
    scale[c] = sc;
    shift[c] = beta[c] - mean * sc;
}

// ---------------- BN apply + ReLU, in place, float4 -----------------------
__global__ void bn_apply_kernel(float4* __restrict__ out, const float* __restrict__ scale,
                                const float* __restrict__ shift, int total4) {
    int i = blockIdx.x * blockDim.x + threadIdx.x;
    if (i >= total4) return;
    int c = (i * 4) & 63;
    float4 v = out[i];
    float a0 = fmaf(v.x, scale[c],     shift[c]);
    float a1 = fmaf(v.y, scale[c + 1], shift[c + 1]);
    float a2 = fmaf(v.z, scale[c + 2], shift[c + 2]);
    float a3 = fmaf(v.w, scale[c + 3], shift[c + 3]);
    v.x = a0 > 0.f ? a0 : 0.f;
    v.y = a1 > 0.f ? a1 : 0.f;
    v.z = a2 > 0.f ? a2 : 0.f;
    v.w = a3 > 0.f ? a3 : 0.f;
    out[i] = v;
}

extern "C" void kernel_launch(void* const* d_in, const int* in_sizes, int n_in,
                              void* d_out, int out_size, void* d_ws, size_t ws_size,
                              hipStream_t stream) {
    const float* x     = (const float*)d_in[0];          // [N, 64]
    const int*   eidx  = (const int*)d_in[1];            // [2, E]
    const float* W     = (const float*)d_in[2];          // [64, 64]
    // d_in[3] = b : cancels in BatchNorm (uniform per-column shift)
    const float* gamma = (const float*)d_in[4];          // [64]
    const float* beta  = (const float*)d_in[5];          // [64]
    float* out = (float*)d_out;                          // [N, 64]

    const int N = N_NODES;
    const int E = N_EDGES;
    const int total = N * DIM;

    const int* src = eidx;
    const int* dst = eidx + E;

    // workspace layout (~21 MB)
    unsigned short* hb = (unsigned short*)d_ws;       // N*DIM bf16 (12.8 MB)
    float* dinv      = (float*)(hb + (size_t)N * DIM);// N
    int*   deg       = (int*)(dinv + N);              // N
    int*   rowptr    = deg + N;                       // N+1
    int*   cursor    = rowptr + N + 1;                // N
    int*   blocksums = cursor + N;                    // 512
    int*   csr_src   = blocksums + 512;               // E (6.4 MB)
    float* gsum      = (float*)(csr_src + E);         // 64
    float* gsumsq    = gsum + 64;                     // 64
    float* scale     = gsumsq + 64;                   // 64
    float* shift     = scale + 64;                    // 64

    hipMemsetAsync(deg, 0, (size_t)N * sizeof(int), stream);
    hipMemsetAsync(gsum, 0, 128 * sizeof(float), stream);

    deg_kernel<<<(E + 255) / 256, 256, 0, stream>>>(dst, deg, E);

    int nb = (N + 255) / 256;  // 391
    scan1_kernel<<<nb, 256, 0, stream>>>(deg, rowptr, blocksums, dinv, N);
    scan2_kernel<<<1, 512, 0, stream>>>(blocksums, nb);
    scan3_kernel<<<(N + 256) / 256, 256, 0, stream>>>(rowptr, cursor, blocksums, N, E);

    gemm_kernel<<<(total + 255) / 256, 256, 0, stream>>>(x, W, dinv, hb, N);

    bucket_kernel<<<(E + 255) / 256, 256, 0, stream>>>(src, dst, cursor, csr_src, E);

    gather_kernel<<<(total + 255) / 256, 256, 0, stream>>>(rowptr, csr_src, hb, dinv, out, N);

    bn_reduce_kernel<<<512, 256, 0, stream>>>(out, gsum, gsumsq, N);
    bn_finalize_kernel<<<1, 64, 0, stream>>>(gsum, gsumsq, gamma, beta, scale, shift, N);
    bn_apply_kernel<<<(total / 4 + 255) / 256, 256, 0, stream>>>((float4*)out, scale, shift, total / 4);
}